// Round 1
// 256.249 us; speedup vs baseline: 1.0106x; 1.0106x over previous
//
#include <hip/hip_runtime.h>
#include <math.h>

#define N_NODES 30000
#define F_IN 256
#define E_RAW 300000
#define E_TOT (E_RAW + N_NODES)   /* 330000: edges + self loops */
#define HEADS 8
#define CH 128
#define HC 1024                   /* HEADS*CH */
#define OUTC 64
#define NEG_SLOPE 0.2f
#define CAP 64                    /* edges per LDS chunk in agg2 */

typedef __attribute__((ext_vector_type(8))) short bf16x8;
typedef __attribute__((ext_vector_type(4))) float f32x4;
typedef __attribute__((ext_vector_type(2))) float f32x2;

/* ---------- helpers ---------- */
__device__ __forceinline__ float bf2f(unsigned short u) {
    return __uint_as_float(((unsigned)u) << 16);
}
__device__ __forceinline__ unsigned short f2bf(float f) {
    unsigned b = __float_as_uint(f);
    b += 0x7FFFu + ((b >> 16) & 1u);   /* round to nearest even */
    return (unsigned short)(b >> 16);
}
__device__ __forceinline__ void edge_sd(const int* __restrict__ ei, int e, int& s, int& d) {
    if (e < E_RAW) { s = ei[e]; d = ei[E_RAW + e]; }
    else           { s = e - E_RAW; d = s; }
}
/* async global->LDS, 16B per lane; LDS dest = wave-uniform base + lane*16 */
__device__ __forceinline__ void async_cp16(const void* g, void* l) {
    __builtin_amdgcn_global_load_lds((const __attribute__((address_space(1))) void*)g,
                                     (__attribute__((address_space(3))) void*)l, 16, 0, 0);
}
/* fp8 slot permutation: slot s -> original channel */
__device__ __forceinline__ int slotP(int s) {
    return ((s >> 6) << 6) + ((s >> 2) & 15) + ((s & 3) << 4);
}
/* wave-local LDS handoff: DS ops from one wave complete in order; we only
   need to stop compiler reordering across the phase boundary. */
__device__ __forceinline__ void wave_sync() {
    __builtin_amdgcn_fence(__ATOMIC_ACQ_REL, "wavefront");
    __builtin_amdgcn_wave_barrier();
}

/* ---------- fused prep: cvt_x | deg | cvt_w1t | cvt_w2t (independent jobs) ---------- */
#define NB_CVTX (N_NODES * F_IN / 4 / 256)      /* 7500 */
#define NB_DEG  ((E_TOT + 255) / 256)           /* 1290 */
#define NB_W1T  ((F_IN * HC + 255) / 256)       /* 1024 */
#define NB_W2T  ((HC * OUTC + 255) / 256)       /* 256 */
#define NB_PREP (NB_CVTX + NB_DEG + NB_W1T + NB_W2T)

__global__ __launch_bounds__(256)
void prep_kernel(const float* __restrict__ x, unsigned short* __restrict__ xb,
                 const float* __restrict__ W1, unsigned short* __restrict__ W1t,
                 const float* __restrict__ W2, unsigned short* __restrict__ W2t,
                 const int* __restrict__ ei, int* __restrict__ deg)
{
    const int b = blockIdx.x, t = threadIdx.x;
    if (b < NB_CVTX) {
        int i = b * 256 + t;
        const float4 v = reinterpret_cast<const float4*>(x)[i];
        ushort4 o;
        o.x = f2bf(v.x); o.y = f2bf(v.y); o.z = f2bf(v.z); o.w = f2bf(v.w);
        reinterpret_cast<ushort4*>(xb)[i] = o;
    } else if (b < NB_CVTX + NB_DEG) {
        int e = (b - NB_CVTX) * 256 + t;
        if (e < E_TOT) {
            int s, d; edge_sd(ei, e, s, d);
            atomicAdd(&deg[d], 1);
        }
    } else if (b < NB_CVTX + NB_DEG + NB_W1T) {
        int i = (b - NB_CVTX - NB_DEG) * 256 + t;
        if (i < F_IN * HC) {
            int k = i >> 10, n = i & (HC - 1);
            W1t[n * F_IN + k] = f2bf(W1[i]);
        }
    } else {
        /* W2t[n][s] = W2[P(s)][n] — k-axis carries the out1 slot permutation */
        int i = (b - NB_CVTX - NB_DEG - NB_W1T) * 256 + t;
        if (i < HC * OUTC) {
            int s = i >> 6, n = i & (OUTC - 1);
            W2t[n * HC + s] = f2bf(W2[slotP(s) * OUTC + n]);
        }
    }
}

/* ---------- layer-1 MFMA GEMM + fused attention dots, fp8 slot-layout C ----------
   R13 form (128x128 tile, BK=64, XOR-swizzled LDS). A-persistent variant (R14)
   regressed: L2 already deduplicated the A re-reads; it added B traffic+barriers. */
__global__ __launch_bounds__(256)
void gemm1_mfma(const unsigned short* __restrict__ A,
                const unsigned short* __restrict__ Bt,
                unsigned* __restrict__ Cp,      /* [M][256] dwords, fp8 slots */
                const float* __restrict__ att_src, const float* __restrict__ att_dst,
                float* __restrict__ a_src, float* __restrict__ a_dst, int M)
{
    __shared__ unsigned short Al[128 * 64];
    __shared__ unsigned short Bl[128 * 64];
    __shared__ float s_src[128][2];
    __shared__ float s_dst[128][2];
    const int tid  = threadIdx.x;
    const int wave = tid >> 6, lane = tid & 63;
    const int quad = lane >> 4, l16 = lane & 15;
    const int wr = (wave >> 1) * 64, wc = (wave & 1) * 64;
    const int row0 = blockIdx.y * 128;
    const int col0 = blockIdx.x * 128;

    f32x4 acc[4][4];
#pragma unroll
    for (int i = 0; i < 4; i++)
#pragma unroll
        for (int j = 0; j < 4; j++) acc[i][j] = (f32x4){0.f, 0.f, 0.f, 0.f};

    for (int k0 = 0; k0 < F_IN; k0 += 64) {
#pragma unroll
        for (int p = 0; p < 4; p++) {           /* A: 128 rows x 64 bf16, swizzled */
            int idx = tid + 256 * p;
            int r = idx >> 3, q = idx & 7;
            async_cp16(A + (size_t)(row0 + r) * F_IN + k0 + ((q ^ (r & 7)) * 8),
                       Al + (size_t)(wave * 64 + 256 * p) * 8);
        }
#pragma unroll
        for (int p = 0; p < 4; p++) {           /* B^T: 128 rows x 64 bf16, swizzled */
            int idx = tid + 256 * p;
            int r = idx >> 3, q = idx & 7;
            async_cp16(Bt + (size_t)(col0 + r) * F_IN + k0 + ((q ^ (r & 7)) * 8),
                       Bl + (size_t)(wave * 64 + 256 * p) * 8);
        }
        __syncthreads();
#pragma unroll
        for (int kh = 0; kh < 2; kh++) {        /* two k-halves, sequential (reg-lean) */
            const int cx = (kh * 4 + quad) ^ (l16 & 7);
            bf16x8 af[4], bg[4];
#pragma unroll
            for (int i = 0; i < 4; i++)
                af[i] = *reinterpret_cast<const bf16x8*>(Al + ((wr + i * 16 + l16) * 8 + cx) * 8);
#pragma unroll
            for (int j = 0; j < 4; j++)
                bg[j] = *reinterpret_cast<const bf16x8*>(Bl + ((wc + j * 16 + l16) * 8 + cx) * 8);
#pragma unroll
            for (int i = 0; i < 4; i++)
#pragma unroll
                for (int j = 0; j < 4; j++)
                    acc[i][j] = __builtin_amdgcn_mfma_f32_16x16x32_bf16(af[i], bg[j], acc[i][j], 0, 0, 0);
        }
        __syncthreads();
    }
    /* C write: pack 4 cols (j=0..3, stride 16) into one fp8 dword at slot-dword D */
    const int D = ((col0 + wc) >> 6) * 16 + l16;
#pragma unroll
    for (int i = 0; i < 4; i++) {
#pragma unroll
        for (int r = 0; r < 4; r++) {
            int row = row0 + wr + i * 16 + quad * 4 + r;
            if (row >= M) continue;
            int w8 = __builtin_amdgcn_cvt_pk_fp8_f32(acc[i][0][r], acc[i][1][r], 0, false);
            w8 = __builtin_amdgcn_cvt_pk_fp8_f32(acc[i][2][r], acc[i][3][r], w8, true);
            Cp[(size_t)row * 256 + D] = (unsigned)w8;
        }
    }
    /* fused attention dots for head = blockIdx.x */
    const float* asv = att_src + blockIdx.x * CH;
    const float* adv = att_dst + blockIdx.x * CH;
    float av[4], dv[4];
#pragma unroll
    for (int j = 0; j < 4; j++) {
        av[j] = asv[wc + j * 16 + l16];
        dv[j] = adv[wc + j * 16 + l16];
    }
#pragma unroll
    for (int i = 0; i < 4; i++) {
#pragma unroll
        for (int r = 0; r < 4; r++) {
            float ps = 0.f, pd = 0.f;
#pragma unroll
            for (int j = 0; j < 4; j++) {
                float cc = acc[i][j][r];
                ps += cc * av[j];
                pd += cc * dv[j];
            }
#pragma unroll
            for (int o = 1; o < 16; o <<= 1) {
                ps += __shfl_xor(ps, o);
                pd += __shfl_xor(pd, o);
            }
            if (l16 == 0) {
                int lr = wr + i * 16 + quad * 4 + r;
                s_src[lr][wc >> 6] = ps;
                s_dst[lr][wc >> 6] = pd;
            }
        }
    }
    __syncthreads();
    if (tid < 128) {
        int row = row0 + tid;
        if (row < M) {
            a_src[row * 8 + blockIdx.x] = s_src[tid][0] + s_src[tid][1];
            a_dst[row * 8 + blockIdx.x] = s_dst[tid][0] + s_dst[tid][1];
        }
    }
}

/* ---------- layer-2 MFMA GEMM + fused att2 dots ----------
   64-row tiles (469 blocks), BK=64 swizzled; wave w owns rows w*16..w*16+15. */
__global__ __launch_bounds__(256)
void gemm2_mfma(const unsigned short* __restrict__ A,
                const unsigned short* __restrict__ Bt,
                unsigned short* __restrict__ C,
                const float* __restrict__ att_src2, const float* __restrict__ att_dst2,
                float* __restrict__ a_src2, float* __restrict__ a_dst2, int M)
{
    __shared__ unsigned short Al[64 * 64];
    __shared__ unsigned short Bl[64 * 64];
    const int tid  = threadIdx.x;
    const int wave = tid >> 6, lane = tid & 63;
    const int quad = lane >> 4, l16 = lane & 15;
    const int wr = wave * 16;
    const int row0 = blockIdx.x * 64;

    f32x4 acc[4];
#pragma unroll
    for (int j = 0; j < 4; j++) acc[j] = (f32x4){0.f, 0.f, 0.f, 0.f};

    for (int k0 = 0; k0 < HC; k0 += 64) {
#pragma unroll
        for (int p = 0; p < 2; p++) {           /* A: 64 rows x 64 bf16, swizzled */
            int idx = tid + 256 * p;
            int r = idx >> 3, q = idx & 7;
            async_cp16(A + (size_t)(row0 + r) * HC + k0 + ((q ^ (r & 7)) * 8),
                       Al + (size_t)(wave * 64 + 256 * p) * 8);
        }
#pragma unroll
        for (int p = 0; p < 2; p++) {           /* B^T: 64 rows x 64 bf16, swizzled */
            int idx = tid + 256 * p;
            int r = idx >> 3, q = idx & 7;
            async_cp16(Bt + (size_t)r * HC + k0 + ((q ^ (r & 7)) * 8),
                       Bl + (size_t)(wave * 64 + 256 * p) * 8);
        }
        __syncthreads();
#pragma unroll
        for (int kh = 0; kh < 2; kh++) {
            const int cx = (kh * 4 + quad) ^ (l16 & 7);
            bf16x8 af, bg[4];
            af = *reinterpret_cast<const bf16x8*>(Al + ((wr + l16) * 8 + cx) * 8);
#pragma unroll
            for (int j = 0; j < 4; j++)
                bg[j] = *reinterpret_cast<const bf16x8*>(Bl + ((j * 16 + l16) * 8 + cx) * 8);
#pragma unroll
            for (int j = 0; j < 4; j++)
                acc[j] = __builtin_amdgcn_mfma_f32_16x16x32_bf16(af, bg[j], acc[j], 0, 0, 0);
        }
        __syncthreads();
    }
    float av[4], dv[4];
#pragma unroll
    for (int j = 0; j < 4; j++) {
        av[j] = att_src2[j * 16 + l16];
        dv[j] = att_dst2[j * 16 + l16];
    }
#pragma unroll
    for (int r = 0; r < 4; r++) {
        int row = row0 + wr + quad * 4 + r;
        float ps = 0.f, pd = 0.f;
#pragma unroll
        for (int j = 0; j < 4; j++) {
            float cc = acc[j][r];
            int col = j * 16 + l16;
            if (row < M) C[(size_t)row * OUTC + col] = f2bf(cc);
            ps += cc * av[j];
            pd += cc * dv[j];
        }
#pragma unroll
        for (int o = 1; o < 16; o <<= 1) {
            ps += __shfl_xor(ps, o);
            pd += __shfl_xor(pd, o);
        }
        if (l16 == 0 && row < M) {
            a_src2[row] = ps;
            a_dst2[row] = pd;
        }
    }
}

/* ---------- CSR build ---------- */
__global__ __launch_bounds__(256)
void alloc_kernel(const int* __restrict__ deg, int* __restrict__ rowstart,
                  int* __restrict__ cursor, int* __restrict__ counter)
{
    int d = blockIdx.x * 256 + threadIdx.x;
    int lane = threadIdx.x & 63;
    int v = (d < N_NODES) ? deg[d] : 0;
    int x = v;
#pragma unroll
    for (int o = 1; o < 64; o <<= 1) {
        int y = __shfl_up(x, o);
        if (lane >= o) x += y;
    }
    int excl = x - v;
    int total = __shfl(x, 63);
    int base = 0;
    if (lane == 63) base = atomicAdd(counter, total);
    base = __shfl(base, 63);
    if (d < N_NODES) {
        rowstart[d] = base + excl;
        cursor[d]   = base + excl;
    }
}

__global__ void scatter_kernel(const int* __restrict__ ei, int* __restrict__ cursor,
                               int* __restrict__ csr_src)
{
    int e = blockIdx.x * 256 + threadIdx.x;
    if (e >= E_TOT) return;
    int s, d; edge_sd(ei, e, s, d);
    int pos = atomicAdd(&cursor[d], 1);
    csr_src[pos] = s;
}

/* ---------- layer-1 fused softmax+aggregation, bias+ELU ----------
   R16: latency fix. Counters showed the old form latency-bound (VALUBusy 44%,
   HBM 60% of achievable, 1-ahead gather pipeline + two dependent LDS phases).
   New form: one wave per node, NO LDS, no wave_syncs. Every lane walks the
   full edge list in 4-edge groups with a 3-stage rotating software pipeline:
     stage A: scalar s_load of csr_src for group G+2 (readfirstlane'd base)
     stage B: issue a_src1 + h1p row loads for group G+1 (8 vmem in flight)
     stage C: consume group G (exp computed redundantly per lane; the
              denominator is then complete per-lane -> no shuffle reduce).
   Invalid tail edges get a = -1e30 (=> w = 0) and a zero row. */
struct SG4 { int s0, s1, s2, s3; };
struct AU4 { float a0, a1, a2, a3; uint4 u0, u1, u2, u3; };

__device__ __forceinline__ SG4 ld_s4(const int* __restrict__ csr_src,
                                     int start, int base, int deg)
{
    SG4 g;
    g.s0 = (base + 0 < deg) ? csr_src[start + base + 0] : -1;
    g.s1 = (base + 1 < deg) ? csr_src[start + base + 1] : -1;
    g.s2 = (base + 2 < deg) ? csr_src[start + base + 2] : -1;
    g.s3 = (base + 3 < deg) ? csr_src[start + base + 3] : -1;
    return g;
}

__device__ __forceinline__ AU4 ld_au4(const float* __restrict__ a_src1,
                                      const uint4* __restrict__ h1v,
                                      SG4 g, int h, int tl)
{
    AU4 r;
    const uint4 z = make_uint4(0u, 0u, 0u, 0u);
    if (g.s0 >= 0) { r.a0 = a_src1[g.s0 * 8 + h]; r.u0 = h1v[(size_t)g.s0 * 64 + tl]; }
    else           { r.a0 = -1e30f; r.u0 = z; }
    if (g.s1 >= 0) { r.a1 = a_src1[g.s1 * 8 + h]; r.u1 = h1v[(size_t)g.s1 * 64 + tl]; }
    else           { r.a1 = -1e30f; r.u1 = z; }
    if (g.s2 >= 0) { r.a2 = a_src1[g.s2 * 8 + h]; r.u2 = h1v[(size_t)g.s2 * 64 + tl]; }
    else           { r.a2 = -1e30f; r.u2 = z; }
    if (g.s3 >= 0) { r.a3 = a_src1[g.s3 * 8 + h]; r.u3 = h1v[(size_t)g.s3 * 64 + tl]; }
    else           { r.a3 = -1e30f; r.u3 = z; }
    return r;
}

#define AGG1_DW(wd_, k_) do { \
    f32x2 lo_ = __builtin_amdgcn_cvt_pk_f32_fp8((int)(wd_), false); \
    f32x2 hi_ = __builtin_amdgcn_cvt_pk_f32_fp8((int)(wd_), true);  \
    acc[(k_) + 0] += w_ * lo_.x; \
    acc[(k_) + 1] += w_ * lo_.y; \
    acc[(k_) + 2] += w_ * hi_.x; \
    acc[(k_) + 3] += w_ * hi_.y; \
} while (0)

#define AGG1_EDGE(aa, uu) do { \
    float al_ = (aa) + adst; \
    float v_ = al_ > 0.f ? al_ : NEG_SLOPE * al_; \
    float w_ = __expf(v_); \
    denom += w_; \
    AGG1_DW((uu).x, 0); AGG1_DW((uu).y, 4); \
    AGG1_DW((uu).z, 8); AGG1_DW((uu).w, 12); \
} while (0)

__global__ __launch_bounds__(256)
void agg1_fused(const int* __restrict__ rowstart, const int* __restrict__ degv,
                const int* __restrict__ csr_src,
                const unsigned* __restrict__ h1p,     /* [N][256] fp8 dwords */
                const float* __restrict__ a_src1, const float* __restrict__ a_dst1,
                const float* __restrict__ b1, unsigned short* __restrict__ out1)
{
    const int t   = threadIdx.x;
    const int sub = t >> 6;            /* node within block: 0..3 (= wave) */
    const int tl  = t & 63;            /* lane within node */
    const int h   = tl >> 3;           /* head (all 16 channels of tl in this head) */
    const int d   = blockIdx.x * 4 + sub;

    /* wave-uniform scalars -> SGPRs so csr_src walks become s_load */
    const int start = __builtin_amdgcn_readfirstlane(rowstart[d]);
    const int deg   = __builtin_amdgcn_readfirstlane(degv[d]);
    const float adst = a_dst1[d * 8 + h];
    const uint4* __restrict__ h1v = reinterpret_cast<const uint4*>(h1p);  /* row = 64 uint4 */

    float denom = 0.f;
    float acc[16];
#pragma unroll
    for (int k = 0; k < 16; k++) acc[k] = 0.f;

    /* pipeline prologue: group 0 fully issued, group 1 s-loads issued */
    SG4 sgN = ld_s4(csr_src, start, 0, deg);
    AU4 auC = ld_au4(a_src1, h1v, sgN, h, tl);
    sgN = ld_s4(csr_src, start, 4, deg);

#pragma unroll 2
    for (int c = 0; c < deg; c += 4) {
        AU4 auN = ld_au4(a_src1, h1v, sgN, h, tl);   /* group c+4 in flight */
        sgN = ld_s4(csr_src, start, c + 8, deg);     /* s for group c+8 */
        AGG1_EDGE(auC.a0, auC.u0);
        AGG1_EDGE(auC.a1, auC.u1);
        AGG1_EDGE(auC.a2, auC.u2);
        AGG1_EDGE(auC.a3, auC.u3);
        auC = auN;
    }

    const float dinv = 1.f / (denom + 1e-16f);

    /* bias (gathered at original channels) + ELU, write bf16 slots 16tl..16tl+15 */
    unsigned short ov[16];
#pragma unroll
    for (int e = 0; e < 16; e++) {
        float v = acc[e] * dinv + b1[slotP(16 * tl + e)];
        v = v > 0.f ? v : __expf(v) - 1.f;
        ov[e] = f2bf(v);
    }
    uint4* op = reinterpret_cast<uint4*>(out1 + (size_t)d * HC + 16 * tl);
    op[0] = *reinterpret_cast<uint4*>(&ov[0]);
    op[1] = *reinterpret_cast<uint4*>(&ov[8]);
}

/* ---------- layer-2 fused softmax+agg + bias + log_softmax ----------
   4 nodes per 256-block, each node = ONE WAVE (wave-local handoff);
   4 edges in flight (16-lane groups); bf16 h2, uint2 loads. */
__global__ __launch_bounds__(256)
void agg2_lsm(const int* __restrict__ rowstart, const int* __restrict__ degv,
              const int* __restrict__ csr_src,
              const unsigned short* __restrict__ h2,
              const float* __restrict__ a_src2, const float* __restrict__ a_dst2,
              const float* __restrict__ b2, float* __restrict__ out)
{
    const int t = threadIdx.x;
    const int sub  = t >> 6;
    const int lane = t & 63;
    const int eo   = lane >> 4;        /* edge offset 0..3 */
    const int cq   = lane & 15;        /* channel quad: channels 4cq..4cq+3 */
    const int d = blockIdx.x * 4 + sub;

    __shared__ float exs[4][CAP];
    __shared__ int   ss[4][CAP];

    const int start = rowstart[d];
    const int deg   = degv[d];

    const float adst = a_dst2[d];
    const uint2* __restrict__ h2v = reinterpret_cast<const uint2*>(h2);  /* row = 16 uint2 */
    float denom_part = 0.f;
    float ax = 0.f, ay = 0.f, az = 0.f, aw = 0.f;

    for (int c0 = 0; c0 < deg; c0 += CAP) {
        const int cend = min(deg - c0, CAP);
        for (int c = lane; c < cend; c += 64) {
            int s = csr_src[start + c0 + c];
            ss[sub][c] = s;
            float a = a_src2[s] + adst;
            float v = a > 0.f ? a : NEG_SLOPE * a;
            float ex = __expf(v);
            exs[sub][c] = ex;
            denom_part += ex;
        }
        wave_sync();
        {
            int   cc = eo;
            float w0 = (cc < cend) ? exs[sub][cc] : 0.f;
            int   s0 = (cc < cend) ? ss[sub][cc] : ss[sub][0];
            uint2 u0 = h2v[(size_t)s0 * 16 + cq];
            for (int c = 0; c + 4 < cend; c += 4) {
                int cc1 = c + 4 + eo;
                float w1 = (cc1 < cend) ? exs[sub][cc1] : 0.f;
                int   s1 = (cc1 < cend) ? ss[sub][cc1] : ss[sub][0];
                uint2 u1 = h2v[(size_t)s1 * 16 + cq];
                ax += w0 * __uint_as_float(u0.x << 16);
                ay += w0 * __uint_as_float(u0.x & 0xFFFF0000u);
                az += w0 * __uint_as_float(u0.y << 16);
                aw += w0 * __uint_as_float(u0.y & 0xFFFF0000u);
                w0 = w1; s0 = s1; u0 = u1;
            }
            ax += w0 * __uint_as_float(u0.x << 16);
            ay += w0 * __uint_as_float(u0.x & 0xFFFF0000u);
            az += w0 * __uint_as_float(u0.y << 16);
            aw += w0 * __uint_as_float(u0.y & 0xFFFF0000u);
        }
        wave_sync();
    }
    /* combine the 4 edge groups: lanes l, l^16, l^32, l^48 share a channel quad */
    ax += __shfl_xor(ax, 16); ax += __shfl_xor(ax, 32);
    ay += __shfl_xor(ay, 16); ay += __shfl_xor(ay, 32);
    az += __shfl_xor(az, 16); az += __shfl_xor(az, 32);
    aw += __shfl_xor(aw, 16); aw += __shfl_xor(aw, 32);
#pragma unroll
    for (int o = 32; o > 0; o >>= 1) denom_part += __shfl_xor(denom_part, o);
    const float dinv = 1.f / (denom_part + 1e-16f);

    float4 bb = reinterpret_cast<const float4*>(b2)[cq];
    float v0 = ax * dinv + bb.x;
    float v1 = ay * dinv + bb.y;
    float v2 = az * dinv + bb.z;
    float v3 = aw * dinv + bb.w;
    float m = fmaxf(fmaxf(v0, v1), fmaxf(v2, v3));
#pragma unroll
    for (int o = 1; o < 16; o <<= 1) m = fmaxf(m, __shfl_xor(m, o));
    float ex = __expf(v0 - m) + __expf(v1 - m) + __expf(v2 - m) + __expf(v3 - m);
    float ssum = ex;
#pragma unroll
    for (int o = 1; o < 16; o <<= 1) ssum += __shfl_xor(ssum, o);
    if (eo == 0) {
        float lg = __logf(ssum);
        reinterpret_cast<float4*>(out + (size_t)d * OUTC)[cq] =
            make_float4(v0 - m - lg, v1 - m - lg, v2 - m - lg, v3 - m - lg);
    }
}

extern "C" void kernel_launch(void* const* d_in, const int* in_sizes, int n_in,
                              void* d_out, int out_size, void* d_ws, size_t ws_size,
                              hipStream_t stream)
{
    const float* x   = (const float*)d_in[0];
    const int*   ei  = (const int*)d_in[1];
    const float* W1  = (const float*)d_in[2];
    const float* as1 = (const float*)d_in[3];
    const float* ad1 = (const float*)d_in[4];
    const float* b1  = (const float*)d_in[5];
    const float* W2  = (const float*)d_in[6];
    const float* as2 = (const float*)d_in[7];
    const float* ad2 = (const float*)d_in[8];
    const float* b2  = (const float*)d_in[9];

    char* p = (char*)d_ws;
    auto alloc = [&](size_t bytes) { char* r = p; p += (bytes + 255) & ~(size_t)255; return r; };

    /* region 0: h1p (fp8, 30.72 MB; sized 61.44) — dead after agg1; layer-2 aliases it */
    char* region0 = (char*)alloc((size_t)N_NODES * HC * 2);
    unsigned* h1p = (unsigned*)region0;

    /* region 1: out1 (bf16 slot-layout, 61.44 MB); xb/W1t (dead after gemm1) alias it */
    char* region1 = (char*)alloc((size_t)N_NODES * HC * 2);
    unsigned short* out1 = (unsigned short*)region1;
    unsigned short* xb   = (unsigned short*)region1;
    unsigned short* W1t  = (unsigned short*)(region1 + (size_t)N_NODES * F_IN * 2 + 256);

    unsigned short* W2t = (unsigned short*)alloc((size_t)OUTC * HC * 2);

    float* a_src1   = (float*)alloc((size_t)N_NODES * HEADS * 4);
    float* a_dst1   = (float*)alloc((size_t)N_NODES * HEADS * 4);
    int*   deg      = (int*)alloc((size_t)(N_NODES + 1) * 4);  /* +1: alloc counter */
    int*   counter  = deg + N_NODES;
    int*   rowstart = (int*)alloc((size_t)N_NODES * 4);
    int*   cursor   = (int*)alloc((size_t)N_NODES * 4);
    int*   csr_src  = (int*)alloc((size_t)E_TOT * 4);

    /* layer-2 buffers aliased into region0 */
    char* q = region0;
    auto alias = [&](size_t bytes) { char* r = q; q += (bytes + 255) & ~(size_t)255; return r; };
    unsigned short* h2 = (unsigned short*)alias((size_t)N_NODES * OUTC * 2);
    float* a_src2  = (float*)alias((size_t)N_NODES * 4);
    float* a_dst2  = (float*)alias((size_t)N_NODES * 4);

    hipMemsetAsync(deg, 0, (size_t)(N_NODES + 1) * 4, stream);

    /* fused prep: cvt_x | deg | cvt_w1t | cvt_w2t */
    prep_kernel<<<NB_PREP, 256, 0, stream>>>(x, xb, W1, W1t, W2, W2t, ei, deg);

    /* CSR build (parallel, unordered ranges) */
    alloc_kernel<<<(N_NODES + 255) / 256, 256, 0, stream>>>(deg, rowstart, cursor, counter);
    scatter_kernel<<<(E_TOT + 255) / 256, 256, 0, stream>>>(ei, cursor, csr_src);

    /* layer 1 (R13 gemm1; att dots fused; h1 stored fp8 slot-layout) */
    gemm1_mfma<<<dim3(HC / 128, (N_NODES + 127) / 128), 256, 0, stream>>>(
        xb, W1t, h1p, as1, ad1, a_src1, a_dst1, N_NODES);
    agg1_fused<<<N_NODES / 4, 256, 0, stream>>>(rowstart, deg, csr_src, h1p, a_src1, a_dst1, b1, out1);

    /* layer 2 (h1p dead; aliased buffers safe, stream-ordered; att2 fused into gemm2) */
    gemm2_mfma<<<(N_NODES + 63) / 64, 256, 0, stream>>>(
        out1, W2t, h2, as2, ad2, a_src2, a_dst2, N_NODES);
    agg2_lsm<<<N_NODES / 4, 256, 0, stream>>>(rowstart, deg, csr_src, h2, a_src2, a_dst2, b2, (float*)d_out);
}